// Round 10
// baseline (55.914 us; speedup 1.0000x reference)
//
#include <hip/hip_runtime.h>
#include <cstddef>

#define NB 128   // #molecules / tokens

typedef short  bf16x8 __attribute__((ext_vector_type(8)));
typedef float  f32x4  __attribute__((ext_vector_type(4)));

// bf16 RNE pack (result in low 16 bits)
__device__ __forceinline__ unsigned int f2bf(float x) {
  unsigned int u = __float_as_uint(x);
  u = (u + 0x7FFFu + ((u >> 16) & 1u)) >> 16;
  return u;
}

// ======================================================================
// K1: blocks 0..127: MFMA-bf16 GNN + pool + fc + qkv(layer0).
//     blocks 128..191: transpose ff1_w -> wT1 (f32, k-major).
// block=256 (4 waves).  Byte-identical to R9 (passed + post-timing stable).
// ======================================================================
__global__ __launch_bounds__(256) void gnn_kernel(
    const int* __restrict__ fp, const float* __restrict__ Aadj,
    const float* __restrict__ embed, const float* __restrict__ Wfp,
    const float* __restrict__ bfp, const float* __restrict__ fc_w,
    const float* __restrict__ fc_b,
    const float* __restrict__ qkv_w, const float* __restrict__ qkv_b,
    const float* __restrict__ ff1_w, float* __restrict__ wT1,
    float* __restrict__ vout, float* __restrict__ qqout)
{
  __shared__ __align__(16) unsigned char smemraw[7 * 9216 + 1536];
  unsigned short* xA  = (unsigned short*)smemraw;
  unsigned short* xB  = xA + 4608;
  unsigned short* hT  = xB + 4608;
  unsigned short* Ab  = hT + 4608;
  unsigned short* Ws0 = Ab + 4608;                  // 3 x 4608 ushorts
  float* prt  = (float*)(smemraw + 7 * 9216);       // [4][64]
  float* mol  = prt + 256;
  float* vloc = mol + 64;

  const int bid = blockIdx.x;
  const int tid = threadIdx.x;

  // ---------------- transpose utility blocks ----------------
  if (bid >= NB) {
    float* xT = (float*)smemraw;       // [64][68] f32 scratch
    const int t = bid - NB;            // 0..63
    const int l = t >> 5, j0 = (t & 31) * 64;
    const float* src = ff1_w + (size_t)l * 131072;
    float*       dst = wT1  + (size_t)l * 131072;
#pragma unroll
    for (int q = 0; q < 4; ++q) {
      int jr = (tid >> 4) + 16 * q, kq = tid & 15;
      float4 vv = *(const float4*)(src + (size_t)(j0 + jr) * 64 + kq * 4);
      *(float4*)&xT[jr * 68 + kq * 4] = vv;
    }
    __syncthreads();
#pragma unroll
    for (int q = 0; q < 4; ++q) {
      int kr = (tid >> 4) + 16 * q, jq = tid & 15;
      float4 ov;
      ov.x = xT[(jq * 4 + 0) * 68 + kr];
      ov.y = xT[(jq * 4 + 1) * 68 + kr];
      ov.z = xT[(jq * 4 + 2) * 68 + kr];
      ov.w = xT[(jq * 4 + 3) * 68 + kr];
      *(float4*)(dst + (size_t)kr * 2048 + j0 + jq * 4) = ov;
    }
    return;
  }

  // ---------------- GNN blocks ----------------
  const int b   = bid;
  const int rt  = tid >> 6;
  const int ln  = tid & 63;
  const int r16 = ln & 15;
  const int kb  = ln >> 4;

  for (int idx = tid; idx < 1024; idx += 256) {     // x0 [atom][k]
    int r = idx >> 4, q = (idx & 15) * 4;
    float4 v = *(const float4*)(embed + (size_t)fp[b * 64 + r] * 64 + q);
    uint2 o;
    o.x = f2bf(v.x) | (f2bf(v.y) << 16);
    o.y = f2bf(v.z) | (f2bf(v.w) << 16);
    *(uint2*)&xA[r * 72 + q] = o;
  }
  for (int idx = tid; idx < 1024; idx += 256) {     // A [i][j]
    int r = idx >> 4, q = (idx & 15) * 4;
    float4 v = *(const float4*)(Aadj + (size_t)(b * 64 + r) * 8192 + b * 64 + q);
    uint2 o;
    o.x = f2bf(v.x) | (f2bf(v.y) << 16);
    o.y = f2bf(v.z) | (f2bf(v.w) << 16);
    *(uint2*)&Ab[r * 72 + q] = o;
  }
  for (int idx = tid; idx < 3072; idx += 256) {     // W_l [o][k]
    int l = idx >> 10, rem = idx & 1023;
    int o = rem >> 4, q = (rem & 15) * 4;
    float4 v = *(const float4*)(Wfp + l * 4096 + o * 64 + q);
    uint2 ov;
    ov.x = f2bf(v.x) | (f2bf(v.y) << 16);
    ov.y = f2bf(v.z) | (f2bf(v.w) << 16);
    *(uint2*)&Ws0[l * 4608 + o * 72 + q] = ov;
  }
  __syncthreads();

  unsigned short* xcur = xA;
  unsigned short* xnxt = xB;
  f32x4 hs[4];

  for (int l = 0; l < 3; ++l) {
    const unsigned short* Wl = Ws0 + l * 4608;

    bf16x8 ax0 = *(const bf16x8*)&xcur[(16 * rt + r16) * 72 + kb * 8];
    bf16x8 ax1 = *(const bf16x8*)&xcur[(16 * rt + r16) * 72 + 32 + kb * 8];
    f32x4 hacc[4];
#pragma unroll
    for (int ct = 0; ct < 4; ++ct) {
      const int o = 16 * ct + r16;
      bf16x8 b0 = *(const bf16x8*)&Wl[o * 72 + kb * 8];
      bf16x8 b1 = *(const bf16x8*)&Wl[o * 72 + 32 + kb * 8];
      float bias = bfp[l * 64 + o];
      f32x4 acc = {bias, bias, bias, bias};
      acc = __builtin_amdgcn_mfma_f32_16x16x32_bf16(ax0, b0, acc, 0, 0, 0);
      acc = __builtin_amdgcn_mfma_f32_16x16x32_bf16(ax1, b1, acc, 0, 0, 0);
      acc[0] = fmaxf(acc[0], 0.f); acc[1] = fmaxf(acc[1], 0.f);
      acc[2] = fmaxf(acc[2], 0.f); acc[3] = fmaxf(acc[3], 0.f);
      hacc[ct] = acc;
      uint2 ov;
      ov.x = f2bf(acc[0]) | (f2bf(acc[1]) << 16);
      ov.y = f2bf(acc[2]) | (f2bf(acc[3]) << 16);
      *(uint2*)&hT[o * 72 + 16 * rt + kb * 4] = ov;
    }
    __syncthreads();

    bf16x8 aa0 = *(const bf16x8*)&Ab[(16 * rt + r16) * 72 + kb * 8];
    bf16x8 aa1 = *(const bf16x8*)&Ab[(16 * rt + r16) * 72 + 32 + kb * 8];
#pragma unroll
    for (int ct = 0; ct < 4; ++ct) {
      const int o = 16 * ct + r16;
      bf16x8 b0 = *(const bf16x8*)&hT[o * 72 + kb * 8];
      bf16x8 b1 = *(const bf16x8*)&hT[o * 72 + 32 + kb * 8];
      f32x4 acc = hacc[ct];
      acc = __builtin_amdgcn_mfma_f32_16x16x32_bf16(aa0, b0, acc, 0, 0, 0);
      acc = __builtin_amdgcn_mfma_f32_16x16x32_bf16(aa1, b1, acc, 0, 0, 0);
      hs[ct] = acc;
    }

    float4 ss;
    ss.x = hs[0][0]*hs[0][0] + hs[1][0]*hs[1][0] + hs[2][0]*hs[2][0] + hs[3][0]*hs[3][0];
    ss.y = hs[0][1]*hs[0][1] + hs[1][1]*hs[1][1] + hs[2][1]*hs[2][1] + hs[3][1]*hs[3][1];
    ss.z = hs[0][2]*hs[0][2] + hs[1][2]*hs[1][2] + hs[2][2]*hs[2][2] + hs[3][2]*hs[3][2];
    ss.w = hs[0][3]*hs[0][3] + hs[1][3]*hs[1][3] + hs[2][3]*hs[2][3] + hs[3][3]*hs[3][3];
#pragma unroll
    for (int m = 1; m <= 8; m <<= 1) {
      ss.x += __shfl_xor(ss.x, m);
      ss.y += __shfl_xor(ss.y, m);
      ss.z += __shfl_xor(ss.z, m);
      ss.w += __shfl_xor(ss.w, m);
    }
    float4 inv;
    inv.x = 1.0f / fmaxf(sqrtf(ss.x), 1e-12f);
    inv.y = 1.0f / fmaxf(sqrtf(ss.y), 1e-12f);
    inv.z = 1.0f / fmaxf(sqrtf(ss.z), 1e-12f);
    inv.w = 1.0f / fmaxf(sqrtf(ss.w), 1e-12f);
#pragma unroll
    for (int ct = 0; ct < 4; ++ct) {
      hs[ct][0] *= inv.x; hs[ct][1] *= inv.y;
      hs[ct][2] *= inv.z; hs[ct][3] *= inv.w;
    }

    if (l < 2) {
#pragma unroll
      for (int ct = 0; ct < 4; ++ct) {
        const int col = 16 * ct + r16;
        xnxt[(16 * rt + kb * 4 + 0) * 72 + col] = (unsigned short)f2bf(hs[ct][0]);
        xnxt[(16 * rt + kb * 4 + 1) * 72 + col] = (unsigned short)f2bf(hs[ct][1]);
        xnxt[(16 * rt + kb * 4 + 2) * 72 + col] = (unsigned short)f2bf(hs[ct][2]);
        xnxt[(16 * rt + kb * 4 + 3) * 72 + col] = (unsigned short)f2bf(hs[ct][3]);
      }
    }
    __syncthreads();

    unsigned short* tmp = xcur; xcur = xnxt; xnxt = tmp;
  }

  {
    float psum[4];
#pragma unroll
    for (int ct = 0; ct < 4; ++ct)
      psum[ct] = hs[ct][0] + hs[ct][1] + hs[ct][2] + hs[ct][3];
#pragma unroll
    for (int ct = 0; ct < 4; ++ct) {
      psum[ct] += __shfl_xor(psum[ct], 16);
      psum[ct] += __shfl_xor(psum[ct], 32);
    }
    if (ln < 16) {
#pragma unroll
      for (int ct = 0; ct < 4; ++ct)
        prt[rt * 64 + 16 * ct + r16] = psum[ct];
    }
  }
  __syncthreads();
  if (tid < 64)
    mol[tid] = prt[tid] + prt[64 + tid] + prt[128 + tid] + prt[192 + tid];
  __syncthreads();
  {
    int d = tid >> 2, q0 = (tid & 3) * 4;
    const float4* wr = (const float4*)(fc_w + d * 64 + q0 * 4);
    float p = 0.f;
#pragma unroll
    for (int i = 0; i < 4; ++i) {
      float4 w4 = wr[i];
      float4 m4 = *(const float4*)&mol[(q0 + i) * 4];
      p += w4.x * m4.x + w4.y * m4.y + w4.z * m4.z + w4.w * m4.w;
    }
    p += __shfl_xor(p, 1); p += __shfl_xor(p, 2);
    if ((tid & 3) == 0) {
      float a = p + fc_b[d];
      vloc[d] = a;
      vout[b * 64 + d] = a;
    }
  }
  __syncthreads();
  if (tid < 192) {
    const float4* wr = (const float4*)(qkv_w + tid * 64);
    float a = qkv_b[tid];
#pragma unroll
    for (int k4 = 0; k4 < 16; ++k4) {
      float4 w4 = wr[k4];
      float4 x4 = *(const float4*)&vloc[k4 * 4];
      a += w4.x * x4.x + w4.y * x4.y + w4.z * x4.z + w4.w * x4.w;
    }
    qqout[(size_t)b * 192 + tid] = a;
  }
}

// ======================================================================
// K2/K3: attention + FF for one layer; then next-layer qkv or head.
// grid=128 (token), block=1024 (16 waves/CU for latency hiding)
// ======================================================================
template <bool LAST>
__global__ __launch_bounds__(1024) void layer_kernel(
    const float* __restrict__ vin, const float* __restrict__ qq_in,
    const float* __restrict__ out_w, const float* __restrict__ out_b,
    const float* __restrict__ ln1_s, const float* __restrict__ ln1_b,
    const float* __restrict__ w1t, const float* __restrict__ ff1_b,
    const float* __restrict__ ff2_w, const float* __restrict__ ff2_b,
    const float* __restrict__ ln2_s, const float* __restrict__ ln2_b,
    const float* __restrict__ nqkv_w, const float* __restrict__ nqkv_b,
    float* __restrict__ qq_out,
    const float* __restrict__ Wout_w, const float* __restrict__ Wout_b,
    const float* __restrict__ Wprop_w, const float* __restrict__ Wprop_b,
    float* __restrict__ vout)
{
  __shared__ __align__(16) float qloc[192];
  __shared__ __align__(16) float Pl[4 * 132];
  __shared__ __align__(16) float cb[2048];
  __shared__ __align__(16) float redt[1024];
  __shared__ __align__(16) float vloc[64];
  __shared__ __align__(16) float vloc2[64];
  __shared__ __align__(16) float osh[64];
  __shared__ __align__(16) float rres[64];
  __shared__ __align__(16) float ffp[64];
  __shared__ float w8b[8];

  const int b   = blockIdx.x;
  const int tid = threadIdx.x;

  if (tid < 64)  vloc[tid] = vin[b * 64 + tid];
  if (tid < 192) qloc[tid] = qq_in[(size_t)b * 192 + tid];
  __syncthreads();

  // ---- scores + softmax (no-max; threads 0..511) ----
  {
    float e = 0.f, sm = 0.f;
    const int j = tid & 127, h = (tid >> 7) & 3;
    if (tid < 512) {
      const float4* qp = (const float4*)&qloc[h * 16];
      const float4* kp = (const float4*)(qq_in + (size_t)j * 192 + 64 + h * 16);
      float s = 0.f;
#pragma unroll
      for (int t = 0; t < 4; ++t) {
        float4 a4 = qp[t], b4 = kp[t];
        s += a4.x * b4.x + a4.y * b4.y + a4.z * b4.z + a4.w * b4.w;
      }
      e = expf(s * 0.25f);
      sm = e;
      for (int off = 32; off; off >>= 1) sm += __shfl_xor(sm, off);
      if ((tid & 63) == 0) w8b[tid >> 6] = sm;
    }
    __syncthreads();
    if (tid < 512) Pl[h * 132 + j] = e / (w8b[2 * h] + w8b[2 * h + 1]);
  }
  __syncthreads();

  // ---- PV: 16 partial slices of 8 keys each ----
  {
    const int d = tid & 63, part = tid >> 6, h2 = d >> 4;
    float a = 0.f;
#pragma unroll
    for (int jj = 0; jj < 8; ++jj) {
      int j2 = part * 8 + jj;
      a += Pl[h2 * 132 + j2] * qq_in[(size_t)j2 * 192 + 128 + d];
    }
    redt[part * 64 + d] = a;
  }
  __syncthreads();
  if (tid < 64) {
    float o = 0.f;
#pragma unroll
    for (int p = 0; p < 16; ++p) o += redt[p * 64 + tid];
    osh[tid] = o;
  }
  __syncthreads();

  // ---- out-proj: 1024-wide, 16 lanes/output, shuffle-16 ----
  {
    int d = tid >> 4, q = tid & 15;
    float4 w4 = *(const float4*)(out_w + d * 64 + q * 4);
    float4 o4 = *(const float4*)&osh[q * 4];
    float p = w4.x * o4.x + w4.y * o4.y + w4.z * o4.z + w4.w * o4.w;
    p += __shfl_xor(p, 1); p += __shfl_xor(p, 2);
    p += __shfl_xor(p, 4); p += __shfl_xor(p, 8);
    if (q == 0) rres[d] = p;
  }
  __syncthreads();

  // ---- residual + LN1 ----
  if (tid < 64) {
    const int d = tid;
    float r = vloc[d] + rres[d] + out_b[d];
    float mu = r;
    for (int off = 32; off; off >>= 1) mu += __shfl_xor(mu, off);
    mu *= (1.0f / 64.0f);
    float df = r - mu;
    float var = df * df;
    for (int off = 32; off; off >>= 1) var += __shfl_xor(var, off);
    var *= (1.0f / 64.0f);
    vloc2[d] = df / sqrtf(var + 1e-5f) * ln1_s[d] + ln1_b[d];
  }
  __syncthreads();

  // ---- FF phase 1: 1024-wide, 2 hidden/thread, f32 k-major w1t ----
  {
    const int j0 = tid * 2;
    float2 a0 = {0.f, 0.f}, a1 = {0.f, 0.f};
#pragma unroll 8
    for (int k = 0; k < 64; k += 2) {
      float v0 = vloc2[k], v1 = vloc2[k + 1];
      float2 w0 = *(const float2*)(w1t + (size_t)k * 2048 + j0);
      float2 w1v = *(const float2*)(w1t + (size_t)(k + 1) * 2048 + j0);
      a0.x += v0 * w0.x; a0.y += v0 * w0.y;
      a1.x += v1 * w1v.x; a1.y += v1 * w1v.y;
    }
    float2 bb = *(const float2*)&ff1_b[j0];
    float2 r;
    r.x = fmaxf(a0.x + a1.x + bb.x, 0.f);
    r.y = fmaxf(a0.y + a1.y + bb.y, 0.f);
    *(float2*)&cb[j0] = r;
  }
  __syncthreads();

  // ---- FF phase 2: 16 waves x 4 rows, coalesced ----
  {
    const int w = tid >> 6, lane = tid & 63;
    const float4* w2f = (const float4*)ff2_w;
    const float4* cbf = (const float4*)cb;
#pragma unroll
    for (int rr = 0; rr < 4; ++rr) {
      int d = w * 4 + rr;
      float p = 0.f;
#pragma unroll
      for (int it = 0; it < 8; ++it) {
        int f = it * 64 + lane;
        float4 wv = w2f[d * 512 + f];
        float4 cv = cbf[f];
        p += wv.x * cv.x + wv.y * cv.y + wv.z * cv.z + wv.w * cv.w;
      }
      for (int off = 32; off; off >>= 1) p += __shfl_xor(p, off);
      if (lane == 0) ffp[d] = p;
    }
  }
  __syncthreads();

  // ---- residual + LN2 -> vloc ----
  if (tid < 64) {
    const int d = tid;
    float r = vloc2[d] + ffp[d] + ff2_b[d];
    float mu = r;
    for (int off = 32; off; off >>= 1) mu += __shfl_xor(mu, off);
    mu *= (1.0f / 64.0f);
    float df = r - mu;
    float var = df * df;
    for (int off = 32; off; off >>= 1) var += __shfl_xor(var, off);
    var *= (1.0f / 64.0f);
    vloc[d] = df / sqrtf(var + 1e-5f) * ln2_s[d] + ln2_b[d];
  }
  __syncthreads();

  if (!LAST) {
    if (tid < 64) vout[b * 64 + tid] = vloc[tid];
    // next-layer qkv: 768-wide, 4 lanes/output, shuffle-4
    if (tid < 768) {
      int o = tid >> 2, q0 = (tid & 3) * 16;
      const float4* wr = (const float4*)(nqkv_w + o * 64 + q0);
      float p = 0.f;
#pragma unroll
      for (int k4 = 0; k4 < 4; ++k4) {
        float4 w4 = wr[k4];
        float4 x4 = *(const float4*)&vloc[q0 + k4 * 4];
        p += w4.x * x4.x + w4.y * x4.y + w4.z * x4.z + w4.w * x4.w;
      }
      p += __shfl_xor(p, 1); p += __shfl_xor(p, 2);
      if ((tid & 3) == 0) qq_out[(size_t)b * 192 + o] = p + nqkv_b[o];
    }
  } else {
    // output head: 1024-wide, 16 lanes/output, shuffle-16, twice
    float* hh0 = redt;
    float* hh1 = redt + 64;
    {
      int d = tid >> 4, q = tid & 15;
      float4 w4 = *(const float4*)(Wout_w + d * 64 + q * 4);
      float4 v4 = *(const float4*)&vloc[q * 4];
      float p = w4.x * v4.x + w4.y * v4.y + w4.z * v4.z + w4.w * v4.w;
      p += __shfl_xor(p, 1); p += __shfl_xor(p, 2);
      p += __shfl_xor(p, 4); p += __shfl_xor(p, 8);
      if (q == 0) hh0[d] = fmaxf(p + Wout_b[d], 0.f);
    }
    __syncthreads();
    {
      int d = tid >> 4, q = tid & 15;
      float4 w4 = *(const float4*)(Wout_w + 4096 + d * 64 + q * 4);
      float4 v4 = *(const float4*)&hh0[q * 4];
      float p = w4.x * v4.x + w4.y * v4.y + w4.z * v4.z + w4.w * v4.w;
      p += __shfl_xor(p, 1); p += __shfl_xor(p, 2);
      p += __shfl_xor(p, 4); p += __shfl_xor(p, 8);
      if (q == 0) hh1[d] = fmaxf(p + Wout_b[64 + d], 0.f);
    }
    __syncthreads();
    if (tid < 2) {
      float a = Wprop_b[tid];
      const float* wr = Wprop_w + tid * 64;
#pragma unroll 8
      for (int c = 0; c < 64; ++c) a += hh1[c] * wr[c];
      vout[b * 2 + tid] = a;
    }
  }
}

// ======================================================================
extern "C" void kernel_launch(void* const* d_in, const int* in_sizes, int n_in,
                              void* d_out, int out_size, void* d_ws, size_t ws_size,
                              hipStream_t stream) {
  const int*   fp      = (const int*)  d_in[0];
  const float* Aadj    = (const float*)d_in[1];
  const float* embed   = (const float*)d_in[2];
  const float* Wfp     = (const float*)d_in[3];
  const float* bfp     = (const float*)d_in[4];
  const float* fc_w    = (const float*)d_in[5];
  const float* fc_b    = (const float*)d_in[6];
  const float* qkv_w   = (const float*)d_in[7];
  const float* qkv_b   = (const float*)d_in[8];
  const float* out_w   = (const float*)d_in[9];
  const float* out_b   = (const float*)d_in[10];
  const float* ln1_s   = (const float*)d_in[11];
  const float* ln1_b   = (const float*)d_in[12];
  const float* ff1_w   = (const float*)d_in[13];
  const float* ff1_b   = (const float*)d_in[14];
  const float* ff2_w   = (const float*)d_in[15];
  const float* ff2_b   = (const float*)d_in[16];
  const float* ln2_s   = (const float*)d_in[17];
  const float* ln2_b   = (const float*)d_in[18];
  const float* Wout_w  = (const float*)d_in[19];
  const float* Wout_b  = (const float*)d_in[20];
  const float* Wprop_w = (const float*)d_in[21];
  const float* Wprop_b = (const float*)d_in[22];
  float* out = (float*)d_out;

  float* ws  = (float*)d_ws;
  float* v0  = ws;             // [128][64]
  float* v1  = ws + 8192;      // [128][64]
  float* qq0 = ws + 16384;     // [128][192]
  float* qq1 = ws + 40960;     // [128][192]
  float* wT1 = ws + 65536;     // 2 x [64][2048] f32 (k-major)

  gnn_kernel<<<dim3(NB + 64), dim3(256), 0, stream>>>(
      fp, Aadj, embed, Wfp, bfp, fc_w, fc_b, qkv_w, qkv_b,
      ff1_w, wT1, v0, qq0);

  layer_kernel<false><<<dim3(NB), dim3(1024), 0, stream>>>(
      v0, qq0, out_w, out_b, ln1_s, ln1_b,
      wT1, ff1_b, ff2_w, ff2_b, ln2_s, ln2_b,
      qkv_w + 12288, qkv_b + 192, qq1,
      nullptr, nullptr, nullptr, nullptr, v1);

  layer_kernel<true><<<dim3(NB), dim3(1024), 0, stream>>>(
      v1, qq1, out_w + 4096, out_b + 64, ln1_s + 64, ln1_b + 64,
      wT1 + 131072, ff1_b + 2048, ff2_w + 131072, ff2_b + 64,
      ln2_s + 64, ln2_b + 64,
      nullptr, nullptr, nullptr,
      Wout_w, Wout_b, Wprop_w, Wprop_b, out);
}

// Round 11
// 49.782 us; speedup vs baseline: 1.1232x; 1.1232x over previous
//
#include <hip/hip_runtime.h>
#include <cstddef>

#define NB 128   // #molecules / tokens

typedef short  bf16x8 __attribute__((ext_vector_type(8)));
typedef float  f32x4  __attribute__((ext_vector_type(4)));

// bf16 RNE pack (result in low 16 bits)
__device__ __forceinline__ unsigned int f2bf(float x) {
  unsigned int u = __float_as_uint(x);
  u = (u + 0x7FFFu + ((u >> 16) & 1u)) >> 16;
  return u;
}

// ======================================================================
// K1: blocks 0..127: MFMA-bf16 GNN + pool + fc + qkv(layer0).
//     blocks 128..191: transpose ff1_w -> wT1 (f32, k-major).
// block=256 (4 waves; wave = row-tile of 16 atoms).
// Hazard-free LDS plan: ping-pong x (xA/xB), W0..W2 staged once
// (read-only after initial sync), hT double-barriered, unconditional
// end-of-layer barrier.  (R9 exact — passed + post-timing stable.)
// ======================================================================
__global__ __launch_bounds__(256) void gnn_kernel(
    const int* __restrict__ fp, const float* __restrict__ Aadj,
    const float* __restrict__ embed, const float* __restrict__ Wfp,
    const float* __restrict__ bfp, const float* __restrict__ fc_w,
    const float* __restrict__ fc_b,
    const float* __restrict__ qkv_w, const float* __restrict__ qkv_b,
    const float* __restrict__ ff1_w, float* __restrict__ wT1,
    float* __restrict__ vout, float* __restrict__ qqout)
{
  // 7 bf16 tiles [64][72] (xA, xB, hT, A, W0, W1, W2) + f32 scratch
  __shared__ __align__(16) unsigned char smemraw[7 * 9216 + 1536];
  unsigned short* xA  = (unsigned short*)smemraw;
  unsigned short* xB  = xA + 4608;
  unsigned short* hT  = xB + 4608;
  unsigned short* Ab  = hT + 4608;
  unsigned short* Ws0 = Ab + 4608;                  // 3 x 4608 ushorts
  float* prt  = (float*)(smemraw + 7 * 9216);       // [4][64]
  float* mol  = prt + 256;
  float* vloc = mol + 64;

  const int bid = blockIdx.x;
  const int tid = threadIdx.x;

  // ---------------- transpose utility blocks ----------------
  if (bid >= NB) {
    float* xT = (float*)smemraw;       // [64][68] f32 scratch
    const int t = bid - NB;            // 0..63
    const int l = t >> 5, j0 = (t & 31) * 64;
    const float* src = ff1_w + (size_t)l * 131072;
    float*       dst = wT1  + (size_t)l * 131072;
#pragma unroll
    for (int q = 0; q < 4; ++q) {
      int jr = (tid >> 4) + 16 * q, kq = tid & 15;
      float4 vv = *(const float4*)(src + (size_t)(j0 + jr) * 64 + kq * 4);
      *(float4*)&xT[jr * 68 + kq * 4] = vv;
    }
    __syncthreads();
#pragma unroll
    for (int q = 0; q < 4; ++q) {
      int kr = (tid >> 4) + 16 * q, jq = tid & 15;
      float4 ov;
      ov.x = xT[(jq * 4 + 0) * 68 + kr];
      ov.y = xT[(jq * 4 + 1) * 68 + kr];
      ov.z = xT[(jq * 4 + 2) * 68 + kr];
      ov.w = xT[(jq * 4 + 3) * 68 + kr];
      *(float4*)(dst + (size_t)kr * 2048 + j0 + jq * 4) = ov;
    }
    return;
  }

  // ---------------- GNN blocks ----------------
  const int b   = bid;
  const int rt  = tid >> 6;          // wave id = row-tile (atoms 16rt..16rt+15)
  const int ln  = tid & 63;
  const int r16 = ln & 15;           // fragment row/col index within tile
  const int kb  = ln >> 4;           // k-block (0..3)

  // ---- stage EVERYTHING once: x0, A, W0..W2 (then one barrier) ----
  for (int idx = tid; idx < 1024; idx += 256) {     // x0 [atom][k]
    int r = idx >> 4, q = (idx & 15) * 4;
    float4 v = *(const float4*)(embed + (size_t)fp[b * 64 + r] * 64 + q);
    uint2 o;
    o.x = f2bf(v.x) | (f2bf(v.y) << 16);
    o.y = f2bf(v.z) | (f2bf(v.w) << 16);
    *(uint2*)&xA[r * 72 + q] = o;
  }
  for (int idx = tid; idx < 1024; idx += 256) {     // A [i][j] (0/1 exact)
    int r = idx >> 4, q = (idx & 15) * 4;
    float4 v = *(const float4*)(Aadj + (size_t)(b * 64 + r) * 8192 + b * 64 + q);
    uint2 o;
    o.x = f2bf(v.x) | (f2bf(v.y) << 16);
    o.y = f2bf(v.z) | (f2bf(v.w) << 16);
    *(uint2*)&Ab[r * 72 + q] = o;
  }
  for (int idx = tid; idx < 3072; idx += 256) {     // W_l [o][k], l=0..2
    int l = idx >> 10, rem = idx & 1023;
    int o = rem >> 4, q = (rem & 15) * 4;
    float4 v = *(const float4*)(Wfp + l * 4096 + o * 64 + q);
    uint2 ov;
    ov.x = f2bf(v.x) | (f2bf(v.y) << 16);
    ov.y = f2bf(v.z) | (f2bf(v.w) << 16);
    *(uint2*)&Ws0[l * 4608 + o * 72 + q] = ov;
  }
  __syncthreads();   // all staged buffers visible; W/A read-only hereafter

  unsigned short* xcur = xA;
  unsigned short* xnxt = xB;
  f32x4 hs[4];       // final-layer normalized fragments survive for pooling

  for (int l = 0; l < 3; ++l) {
    const unsigned short* Wl = Ws0 + l * 4608;

    // ---- phase 1: h = relu(x @ W^T + b) via MFMA; write hT (own cols) ----
    bf16x8 ax0 = *(const bf16x8*)&xcur[(16 * rt + r16) * 72 + kb * 8];
    bf16x8 ax1 = *(const bf16x8*)&xcur[(16 * rt + r16) * 72 + 32 + kb * 8];
    f32x4 hacc[4];
#pragma unroll
    for (int ct = 0; ct < 4; ++ct) {
      const int o = 16 * ct + r16;
      bf16x8 b0 = *(const bf16x8*)&Wl[o * 72 + kb * 8];
      bf16x8 b1 = *(const bf16x8*)&Wl[o * 72 + 32 + kb * 8];
      float bias = bfp[l * 64 + o];
      f32x4 acc = {bias, bias, bias, bias};
      acc = __builtin_amdgcn_mfma_f32_16x16x32_bf16(ax0, b0, acc, 0, 0, 0);
      acc = __builtin_amdgcn_mfma_f32_16x16x32_bf16(ax1, b1, acc, 0, 0, 0);
      acc[0] = fmaxf(acc[0], 0.f); acc[1] = fmaxf(acc[1], 0.f);
      acc[2] = fmaxf(acc[2], 0.f); acc[3] = fmaxf(acc[3], 0.f);
      hacc[ct] = acc;
      uint2 ov;
      ov.x = f2bf(acc[0]) | (f2bf(acc[1]) << 16);
      ov.y = f2bf(acc[2]) | (f2bf(acc[3]) << 16);
      *(uint2*)&hT[o * 72 + 16 * rt + kb * 4] = ov;
    }
    __syncthreads();   // hT fully written

    // ---- phase 2: hs = h + A @ h via MFMA (C-init = f32 h fragments) ----
    bf16x8 aa0 = *(const bf16x8*)&Ab[(16 * rt + r16) * 72 + kb * 8];
    bf16x8 aa1 = *(const bf16x8*)&Ab[(16 * rt + r16) * 72 + 32 + kb * 8];
#pragma unroll
    for (int ct = 0; ct < 4; ++ct) {
      const int o = 16 * ct + r16;
      bf16x8 b0 = *(const bf16x8*)&hT[o * 72 + kb * 8];
      bf16x8 b1 = *(const bf16x8*)&hT[o * 72 + 32 + kb * 8];
      f32x4 acc = hacc[ct];
      acc = __builtin_amdgcn_mfma_f32_16x16x32_bf16(aa0, b0, acc, 0, 0, 0);
      acc = __builtin_amdgcn_mfma_f32_16x16x32_bf16(aa1, b1, acc, 0, 0, 0);
      hs[ct] = acc;
    }

    // ---- row L2 norm on fragments (lane: rows 16rt+4kb+j, col 16ct+r16) ----
    float4 ss;
    ss.x = hs[0][0]*hs[0][0] + hs[1][0]*hs[1][0] + hs[2][0]*hs[2][0] + hs[3][0]*hs[3][0];
    ss.y = hs[0][1]*hs[0][1] + hs[1][1]*hs[1][1] + hs[2][1]*hs[2][1] + hs[3][1]*hs[3][1];
    ss.z = hs[0][2]*hs[0][2] + hs[1][2]*hs[1][2] + hs[2][2]*hs[2][2] + hs[3][2]*hs[3][2];
    ss.w = hs[0][3]*hs[0][3] + hs[1][3]*hs[1][3] + hs[2][3]*hs[2][3] + hs[3][3]*hs[3][3];
#pragma unroll
    for (int m = 1; m <= 8; m <<= 1) {   // reduce over the 16 r16-lanes (cols)
      ss.x += __shfl_xor(ss.x, m);
      ss.y += __shfl_xor(ss.y, m);
      ss.z += __shfl_xor(ss.z, m);
      ss.w += __shfl_xor(ss.w, m);
    }
    float4 inv;
    inv.x = 1.0f / fmaxf(sqrtf(ss.x), 1e-12f);
    inv.y = 1.0f / fmaxf(sqrtf(ss.y), 1e-12f);
    inv.z = 1.0f / fmaxf(sqrtf(ss.z), 1e-12f);
    inv.w = 1.0f / fmaxf(sqrtf(ss.w), 1e-12f);
#pragma unroll
    for (int ct = 0; ct < 4; ++ct) {
      hs[ct][0] *= inv.x; hs[ct][1] *= inv.y;
      hs[ct][2] *= inv.z; hs[ct][3] *= inv.w;
    }

    if (l < 2) {
      // write x_{l+1} into the OTHER buffer (wave-local rows, scattered u16)
#pragma unroll
      for (int ct = 0; ct < 4; ++ct) {
        const int col = 16 * ct + r16;
        xnxt[(16 * rt + kb * 4 + 0) * 72 + col] = (unsigned short)f2bf(hs[ct][0]);
        xnxt[(16 * rt + kb * 4 + 1) * 72 + col] = (unsigned short)f2bf(hs[ct][1]);
        xnxt[(16 * rt + kb * 4 + 2) * 72 + col] = (unsigned short)f2bf(hs[ct][2]);
        xnxt[(16 * rt + kb * 4 + 3) * 72 + col] = (unsigned short)f2bf(hs[ct][3]);
      }
    }
    __syncthreads();   // UNCONDITIONAL end-of-layer barrier (hT reuse fence)

    unsigned short* tmp = xcur; xcur = xnxt; xnxt = tmp;
  }

  // ---- pool from final fragments: mol[k] = sum_atoms x[.,k] ----
  {
    float psum[4];
#pragma unroll
    for (int ct = 0; ct < 4; ++ct)
      psum[ct] = hs[ct][0] + hs[ct][1] + hs[ct][2] + hs[ct][3];
#pragma unroll
    for (int ct = 0; ct < 4; ++ct) {   // reduce across kb groups (row blocks)
      psum[ct] += __shfl_xor(psum[ct], 16);
      psum[ct] += __shfl_xor(psum[ct], 32);
    }
    if (ln < 16) {
#pragma unroll
      for (int ct = 0; ct < 4; ++ct)
        prt[rt * 64 + 16 * ct + r16] = psum[ct];
    }
  }
  __syncthreads();
  if (tid < 64)
    mol[tid] = prt[tid] + prt[64 + tid] + prt[128 + tid] + prt[192 + tid];
  __syncthreads();
  // fc: 256-wide, shuffle-4
  {
    int d = tid >> 2, q0 = (tid & 3) * 4;
    const float4* wr = (const float4*)(fc_w + d * 64 + q0 * 4);
    float p = 0.f;
#pragma unroll
    for (int i = 0; i < 4; ++i) {
      float4 w4 = wr[i];
      float4 m4 = *(const float4*)&mol[(q0 + i) * 4];
      p += w4.x * m4.x + w4.y * m4.y + w4.z * m4.z + w4.w * m4.w;
    }
    p += __shfl_xor(p, 1); p += __shfl_xor(p, 2);
    if ((tid & 3) == 0) {
      float a = p + fc_b[d];
      vloc[d] = a;
      vout[b * 64 + d] = a;
    }
  }
  __syncthreads();
  if (tid < 192) {   // layer-0 qkv
    const float4* wr = (const float4*)(qkv_w + tid * 64);
    float a = qkv_b[tid];
#pragma unroll
    for (int k4 = 0; k4 < 16; ++k4) {
      float4 w4 = wr[k4];
      float4 x4 = *(const float4*)&vloc[k4 * 4];
      a += w4.x * x4.x + w4.y * x4.y + w4.z * x4.z + w4.w * x4.w;
    }
    qqout[(size_t)b * 192 + tid] = a;
  }
}

// ======================================================================
// K2/K3: attention + FF for one layer; then next-layer qkv or head.
// grid=128 (token), block=512.  (R7/R9 exact — proven
// post-timing-deterministic.)
// ======================================================================
template <bool LAST>
__global__ __launch_bounds__(512) void layer_kernel(
    const float* __restrict__ vin, const float* __restrict__ qq_in,
    const float* __restrict__ out_w, const float* __restrict__ out_b,
    const float* __restrict__ ln1_s, const float* __restrict__ ln1_b,
    const float* __restrict__ w1t, const float* __restrict__ ff1_b,
    const float* __restrict__ ff2_w, const float* __restrict__ ff2_b,
    const float* __restrict__ ln2_s, const float* __restrict__ ln2_b,
    const float* __restrict__ nqkv_w, const float* __restrict__ nqkv_b,
    float* __restrict__ qq_out,
    const float* __restrict__ Wout_w, const float* __restrict__ Wout_b,
    const float* __restrict__ Wprop_w, const float* __restrict__ Wprop_b,
    float* __restrict__ vout)
{
  __shared__ __align__(16) float qloc[192];
  __shared__ __align__(16) float Pl[4 * 132];
  __shared__ __align__(16) float cb[2048];
  __shared__ __align__(16) float redt[512];
  __shared__ __align__(16) float vloc[64];
  __shared__ __align__(16) float vloc2[64];
  __shared__ __align__(16) float osh[64];
  __shared__ __align__(16) float rres[64];
  __shared__ __align__(16) float ffp[64];
  __shared__ float w8b[8];

  const int b   = blockIdx.x;
  const int tid = threadIdx.x;

  if (tid < 64)  vloc[tid] = vin[b * 64 + tid];
  if (tid < 192) qloc[tid] = qq_in[(size_t)b * 192 + tid];
  __syncthreads();

  // ---- scores + softmax (no-max: |s| tiny, exp safe) ----
  {
    const int j = tid & 127, h = tid >> 7;
    const float4* qp = (const float4*)&qloc[h * 16];
    const float4* kp = (const float4*)(qq_in + (size_t)j * 192 + 64 + h * 16);
    float s = 0.f;
#pragma unroll
    for (int t = 0; t < 4; ++t) {
      float4 a4 = qp[t], b4 = kp[t];
      s += a4.x * b4.x + a4.y * b4.y + a4.z * b4.z + a4.w * b4.w;
    }
    float e = expf(s * 0.25f);
    float sm = e;
    for (int off = 32; off; off >>= 1) sm += __shfl_xor(sm, off);
    if ((tid & 63) == 0) w8b[tid >> 6] = sm;
    __syncthreads();
    Pl[h * 132 + j] = e / (w8b[2 * h] + w8b[2 * h + 1]);
  }
  __syncthreads();

  // ---- PV ----
  {
    const int d = tid & 63, part = tid >> 6, h2 = d >> 4;
    float a = 0.f;
#pragma unroll
    for (int jj = 0; jj < 16; ++jj) {
      int j2 = part * 16 + jj;
      a += Pl[h2 * 132 + j2] * qq_in[(size_t)j2 * 192 + 128 + d];
    }
    redt[part * 64 + d] = a;
  }
  __syncthreads();
  if (tid < 64) {
    float o = 0.f;
#pragma unroll
    for (int p = 0; p < 8; ++p) o += redt[p * 64 + tid];
    osh[tid] = o;
  }
  __syncthreads();

  // ---- out-proj: 512-wide, shuffle-8 ----
  {
    int d = tid >> 3, q0 = (tid & 7) * 2;
    const float4* wr = (const float4*)(out_w + d * 64 + q0 * 4);
    float p = 0.f;
#pragma unroll
    for (int i = 0; i < 2; ++i) {
      float4 w4 = wr[i];
      float4 o4 = *(const float4*)&osh[(q0 + i) * 4];
      p += w4.x * o4.x + w4.y * o4.y + w4.z * o4.z + w4.w * o4.w;
    }
    p += __shfl_xor(p, 1); p += __shfl_xor(p, 2); p += __shfl_xor(p, 4);
    if ((tid & 7) == 0) rres[d] = p;
  }
  __syncthreads();

  // ---- residual + LN1 ----
  if (tid < 64) {
    const int d = tid;
    float r = vloc[d] + rres[d] + out_b[d];
    float mu = r;
    for (int off = 32; off; off >>= 1) mu += __shfl_xor(mu, off);
    mu *= (1.0f / 64.0f);
    float df = r - mu;
    float var = df * df;
    for (int off = 32; off; off >>= 1) var += __shfl_xor(var, off);
    var *= (1.0f / 64.0f);
    vloc2[d] = df / sqrtf(var + 1e-5f) * ln1_s[d] + ln1_b[d];
  }
  __syncthreads();

  // ---- FF phase 1: f32 transposed w1 (k-major), coalesced ----
  {
    const float4* wt = (const float4*)w1t;
    float4 a0 = {0.f, 0.f, 0.f, 0.f}, a1 = {0.f, 0.f, 0.f, 0.f};
#pragma unroll 8
    for (int k = 0; k < 64; k += 2) {
      float v0 = vloc2[k], v1 = vloc2[k + 1];
      float4 w0 = wt[(size_t)k * 512 + tid];
      float4 w1v = wt[(size_t)(k + 1) * 512 + tid];
      a0.x += v0 * w0.x; a0.y += v0 * w0.y; a0.z += v0 * w0.z; a0.w += v0 * w0.w;
      a1.x += v1 * w1v.x; a1.y += v1 * w1v.y; a1.z += v1 * w1v.z; a1.w += v1 * w1v.w;
    }
    const int j0 = tid * 4;
    float4 bb = *(const float4*)&ff1_b[j0];
    float4 r;
    r.x = fmaxf(a0.x + a1.x + bb.x, 0.f);
    r.y = fmaxf(a0.y + a1.y + bb.y, 0.f);
    r.z = fmaxf(a0.z + a1.z + bb.z, 0.f);
    r.w = fmaxf(a0.w + a1.w + bb.w, 0.f);
    *(float4*)&cb[j0] = r;
  }
  __syncthreads();

  // ---- FF phase 2: wave owns 8 rows, coalesced ----
  {
    const int w = tid >> 6, lane = tid & 63;
    const float4* w2f = (const float4*)ff2_w;
    const float4* cbf = (const float4*)cb;
#pragma unroll
    for (int rr = 0; rr < 8; ++rr) {
      int d = w * 8 + rr;
      float p = 0.f;
#pragma unroll
      for (int it = 0; it < 8; ++it) {
        int f = it * 64 + lane;
        float4 wv = w2f[d * 512 + f];
        float4 cv = cbf[f];
        p += wv.x * cv.x + wv.y * cv.y + wv.z * cv.z + wv.w * cv.w;
      }
      for (int off = 32; off; off >>= 1) p += __shfl_xor(p, off);
      if (lane == 0) ffp[d] = p;
    }
  }
  __syncthreads();

  // ---- residual + LN2 -> vloc ----
  if (tid < 64) {
    const int d = tid;
    float r = vloc2[d] + ffp[d] + ff2_b[d];
    float mu = r;
    for (int off = 32; off; off >>= 1) mu += __shfl_xor(mu, off);
    mu *= (1.0f / 64.0f);
    float df = r - mu;
    float var = df * df;
    for (int off = 32; off; off >>= 1) var += __shfl_xor(var, off);
    var *= (1.0f / 64.0f);
    vloc[d] = df / sqrtf(var + 1e-5f) * ln2_s[d] + ln2_b[d];
  }
  __syncthreads();

  if (!LAST) {
    if (tid < 64) vout[b * 64 + tid] = vloc[tid];
    if (tid < 384) {   // next-layer qkv: 384-wide, shuffle-2
      int o = tid >> 1, q0 = (tid & 1) * 32;
      const float4* wr = (const float4*)(nqkv_w + o * 64 + q0);
      float p = 0.f;
#pragma unroll
      for (int k4 = 0; k4 < 8; ++k4) {
        float4 w4 = wr[k4];
        float4 x4 = *(const float4*)&vloc[q0 + k4 * 4];
        p += w4.x * x4.x + w4.y * x4.y + w4.z * x4.z + w4.w * x4.w;
      }
      p += __shfl_xor(p, 1);
      if ((tid & 1) == 0) qq_out[(size_t)b * 192 + o] = p + nqkv_b[o];
    }
  } else {
    // output head: 512-wide shuffle-8 for both 64x64 layers
    {
      int d = tid >> 3, q0 = (tid & 7) * 2;
      const float4* wr = (const float4*)(Wout_w + d * 64 + q0 * 4);
      float p = 0.f;
#pragma unroll
      for (int i = 0; i < 2; ++i) {
        float4 w4 = wr[i];
        float4 v4 = *(const float4*)&vloc[(q0 + i) * 4];
        p += w4.x * v4.x + w4.y * v4.y + w4.z * v4.z + w4.w * v4.w;
      }
      p += __shfl_xor(p, 1); p += __shfl_xor(p, 2); p += __shfl_xor(p, 4);
      if ((tid & 7) == 0) redt[d] = fmaxf(p + Wout_b[d], 0.f);
    }
    __syncthreads();
    {
      int d = tid >> 3, q0 = (tid & 7) * 2;
      const float4* wr = (const float4*)(Wout_w + 4096 + d * 64 + q0 * 4);
      float p = 0.f;
#pragma unroll
      for (int i = 0; i < 2; ++i) {
        float4 w4 = wr[i];
        float4 v4 = *(const float4*)&redt[(q0 + i) * 4];
        p += w4.x * v4.x + w4.y * v4.y + w4.z * v4.z + w4.w * v4.w;
      }
      p += __shfl_xor(p, 1); p += __shfl_xor(p, 2); p += __shfl_xor(p, 4);
      if ((tid & 7) == 0) redt[64 + d] = fmaxf(p + Wout_b[64 + d], 0.f);
    }
    __syncthreads();
    if (tid < 2) {
      float a = Wprop_b[tid];
      const float* wr = Wprop_w + tid * 64;
#pragma unroll 8
      for (int c = 0; c < 64; ++c) a += redt[64 + c] * wr[c];
      vout[b * 2 + tid] = a;
    }
  }
}

// ======================================================================
extern "C" void kernel_launch(void* const* d_in, const int* in_sizes, int n_in,
                              void* d_out, int out_size, void* d_ws, size_t ws_size,
                              hipStream_t stream) {
  const int*   fp      = (const int*)  d_in[0];
  const float* Aadj    = (const float*)d_in[1];
  const float* embed   = (const float*)d_in[2];
  const float* Wfp     = (const float*)d_in[3];
  const float* bfp     = (const float*)d_in[4];
  const float* fc_w    = (const float*)d_in[5];
  const float* fc_b    = (const float*)d_in[6];
  const float* qkv_w   = (const float*)d_in[7];
  const float* qkv_b   = (const float*)d_in[8];
  const float* out_w   = (const float*)d_in[9];
  const float* out_b   = (const float*)d_in[10];
  const float* ln1_s   = (const float*)d_in[11];
  const float* ln1_b   = (const float*)d_in[12];
  const float* ff1_w   = (const float*)d_in[13];
  const float* ff1_b   = (const float*)d_in[14];
  const float* ff2_w   = (const float*)d_in[15];
  const float* ff2_b   = (const float*)d_in[16];
  const float* ln2_s   = (const float*)d_in[17];
  const float* ln2_b   = (const float*)d_in[18];
  const float* Wout_w  = (const float*)d_in[19];
  const float* Wout_b  = (const float*)d_in[20];
  const float* Wprop_w = (const float*)d_in[21];
  const float* Wprop_b = (const float*)d_in[22];
  float* out = (float*)d_out;

  float* ws  = (float*)d_ws;
  float* v0  = ws;             // [128][64]
  float* v1  = ws + 8192;      // [128][64]
  float* qq0 = ws + 16384;     // [128][192]
  float* qq1 = ws + 40960;     // [128][192]
  float* wT1 = ws + 65536;     // 2 x [64][2048] f32 (k-major)

  gnn_kernel<<<dim3(NB + 64), dim3(256), 0, stream>>>(
      fp, Aadj, embed, Wfp, bfp, fc_w, fc_b, qkv_w, qkv_b,
      ff1_w, wT1, v0, qq0);

  layer_kernel<false><<<dim3(NB), dim3(512), 0, stream>>>(
      v0, qq0, out_w, out_b, ln1_s, ln1_b,
      wT1, ff1_b, ff2_w, ff2_b, ln2_s, ln2_b,
      qkv_w + 12288, qkv_b + 192, qq1,
      nullptr, nullptr, nullptr, nullptr, v1);

  layer_kernel<true><<<dim3(NB), dim3(512), 0, stream>>>(
      v1, qq1, out_w + 4096, out_b + 64, ln1_s + 64, ln1_b + 64,
      wT1 + 131072, ff1_b + 2048, ff2_w + 131072, ff2_b + 64,
      ln2_s + 64, ln2_b + 64,
      nullptr, nullptr, nullptr,
      Wout_w, Wout_b, Wprop_w, Wprop_b, out);
}